// Round 1
// baseline (425.727 us; speedup 1.0000x reference)
//
#include <hip/hip_runtime.h>

// Biquad DF2T over [B=512, T=48000] fp32, per-channel coeffs.
// Single-scan register-resident design:
//   - one block per channel, 512 threads (500 active), 96 samples/thread
//   - whole subchunk lives in 24 float4 VGPRs (no LDS staging of x)
//   - local zero-state response -> (P = A^96, w) per thread
//   - intra-wave Kogge-Stone scan via __shfl_up (no barriers),
//     single __syncthreads to combine 8 wave aggregates (48 B LDS)
//   - replay with exact reference arithmetic, nontemporal float4 stores
// Barriers per block: 1 (was ~88). Traffic: x read once, y written once.

#define B_CH   512
#define T_LEN  48000
#define NACT   500          // active threads per block
#define L      96           // samples per thread  (NACT * L == T_LEN)
#define NF4    (L / 4)      // 24 float4 per thread
#define NWAVE  8

typedef float f4_t __attribute__((ext_vector_type(4)));

__global__ __launch_bounds__(512, 4) void k_biquad_scan(
    const float* __restrict__ x,
    const float* __restrict__ b0v, const float* __restrict__ b1v,
    const float* __restrict__ b2v,
    const float* __restrict__ a1v, const float* __restrict__ a2v,
    float* __restrict__ y)
{
    __shared__ float aggP[NWAVE][4];   // wave-aggregate transforms
    __shared__ float aggW[NWAVE][2];   // wave-aggregate responses

    const int b    = blockIdx.x;
    const int t    = threadIdx.x;
    const int lane = t & 63;
    const int wid  = t >> 6;

    const float A1 = a1v[b], A2 = a2v[b];
    const float B0 = b0v[b], B1 = b1v[b], B2 = b2v[b];
    // y-eliminated state form: z1' = c1*x - a1*z1 + z2 ; z2' = c2*x - a2*z1
    const float c1 = B1 - A1 * B0;
    const float c2 = B2 - A2 * B0;

    const float* __restrict__ xb = x + (size_t)b * T_LEN;
    float*       __restrict__ yb = y + (size_t)b * T_LEN;

    // ---- issue all 24 global float4 loads up front (strided per-thread
    //      chunks: each thread reads a contiguous 384 B; a wave covers a
    //      contiguous 24 KB so every fetched line is consumed)
    f4_t xr[NF4];
    if (t < NACT) {
        const f4_t* p = (const f4_t*)(xb + t * L);
        #pragma unroll
        for (int i = 0; i < NF4; ++i) xr[i] = p[i];
    }

    // ---- G = A^L, A = [[-a1,1],[-a2,0]]  (overlaps the load latency)
    float G00, G01, G10, G11;
    {
        float m00 = -A1, m01 = 1.f, m10 = -A2, m11 = 0.f;
        float f00 = 1.f, f01 = 0.f, f10 = 0.f, f11 = 1.f;
        int e = L;
        while (e) {
            if (e & 1) {
                const float t00 = f00*m00 + f01*m10, t01 = f00*m01 + f01*m11;
                const float t10 = f10*m00 + f11*m10, t11 = f10*m01 + f11*m11;
                f00 = t00; f01 = t01; f10 = t10; f11 = t11;
            }
            e >>= 1;
            if (!e) break;
            const float s00 = m00*m00 + m01*m10, s01 = m00*m01 + m01*m11;
            const float s10 = m10*m00 + m11*m10, s11 = m10*m01 + m11*m11;
            m00 = s00; m01 = s01; m10 = s10; m11 = s11;
        }
        G00 = f00; G01 = f01; G10 = f10; G11 = f11;
    }

    // ---- local zero-state response over own 96 samples
    float P00, P01, P10, P11, w0, w1;
    if (t < NACT) {
        float z1 = 0.f, z2 = 0.f;
        #pragma unroll
        for (int i = 0; i < NF4; ++i) {
            const f4_t v = xr[i];
            { const float xn = v.x; const float n1 = c1*xn + z2 - A1*z1; z2 = c2*xn - A2*z1; z1 = n1; }
            { const float xn = v.y; const float n1 = c1*xn + z2 - A1*z1; z2 = c2*xn - A2*z1; z1 = n1; }
            { const float xn = v.z; const float n1 = c1*xn + z2 - A1*z1; z2 = c2*xn - A2*z1; z1 = n1; }
            { const float xn = v.w; const float n1 = c1*xn + z2 - A1*z1; z2 = c2*xn - A2*z1; z1 = n1; }
        }
        P00 = G00; P01 = G01; P10 = G10; P11 = G11; w0 = z1; w1 = z2;
    } else {
        P00 = 1.f; P01 = 0.f; P10 = 0.f; P11 = 1.f; w0 = 0.f; w1 = 0.f;
    }

    // ---- intra-wave inclusive Kogge-Stone scan via shuffles (no barriers)
    //      combine: self after prev:  P := P·E ; w := P·ew + w
    #pragma unroll
    for (int off = 1; off < 64; off <<= 1) {
        const float e00 = __shfl_up(P00, off);
        const float e01 = __shfl_up(P01, off);
        const float e10 = __shfl_up(P10, off);
        const float e11 = __shfl_up(P11, off);
        const float s0  = __shfl_up(w0,  off);
        const float s1  = __shfl_up(w1,  off);
        if (lane >= off) {
            const float n00 = P00*e00 + P01*e10, n01 = P00*e01 + P01*e11;
            const float n10 = P10*e00 + P11*e10, n11 = P10*e01 + P11*e11;
            w0 = P00*s0 + P01*s1 + w0;
            w1 = P10*s0 + P11*s1 + w1;
            P00 = n00; P01 = n01; P10 = n10; P11 = n11;
        }
    }

    // publish wave aggregates (lane 63 inclusive = whole-wave transform)
    if (lane == 63) {
        aggP[wid][0] = P00; aggP[wid][1] = P01;
        aggP[wid][2] = P10; aggP[wid][3] = P11;
        aggW[wid][0] = w0;  aggW[wid][1] = w1;
    }

    // exclusive-within-wave transform = inclusive shifted by one lane
    float E00 = __shfl_up(P00, 1), E01 = __shfl_up(P01, 1);
    float E10 = __shfl_up(P10, 1), E11 = __shfl_up(P11, 1);
    float Ew0 = __shfl_up(w0, 1),  Ew1 = __shfl_up(w1, 1);
    if (lane == 0) { E00 = 1.f; E01 = 0.f; E10 = 0.f; E11 = 1.f; Ew0 = 0.f; Ew1 = 0.f; }

    __syncthreads();   // the only barrier in the kernel

    // fold aggregates of preceding waves (wave-uniform loop, <=7 iters;
    // global initial state is zero so only the w-vector is needed)
    float wc0 = 0.f, wc1 = 0.f;
    for (int k = 0; k < wid; ++k) {
        const float p0 = aggP[k][0], p1 = aggP[k][1];
        const float p2 = aggP[k][2], p3 = aggP[k][3];
        const float q0 = aggW[k][0], q1 = aggW[k][1];
        const float n0 = p0*wc0 + p1*wc1 + q0;
        const float n1 = p2*wc0 + p3*wc1 + q1;
        wc0 = n0; wc1 = n1;
    }

    // this thread's true initial state
    float z1 = E00*wc0 + E01*wc1 + Ew0;
    float z2 = E10*wc0 + E11*wc1 + Ew1;

    // ---- replay with exact reference arithmetic, nontemporal stores
    if (t < NACT) {
        f4_t* q = (f4_t*)(yb + t * L);
        #pragma unroll
        for (int i = 0; i < NF4; ++i) {
            const f4_t v = xr[i];
            f4_t o;
            { const float xn = v.x; const float yn = B0*xn + z1; o.x = yn;
              const float n1 = B1*xn - A1*yn + z2; z2 = B2*xn - A2*yn; z1 = n1; }
            { const float xn = v.y; const float yn = B0*xn + z1; o.y = yn;
              const float n1 = B1*xn - A1*yn + z2; z2 = B2*xn - A2*yn; z1 = n1; }
            { const float xn = v.z; const float yn = B0*xn + z1; o.z = yn;
              const float n1 = B1*xn - A1*yn + z2; z2 = B2*xn - A2*yn; z1 = n1; }
            { const float xn = v.w; const float yn = B0*xn + z1; o.w = yn;
              const float n1 = B1*xn - A1*yn + z2; z2 = B2*xn - A2*yn; z1 = n1; }
            __builtin_nontemporal_store(o, q + i);
        }
    }
}

extern "C" void kernel_launch(void* const* d_in, const int* in_sizes, int n_in,
                              void* d_out, int out_size, void* d_ws, size_t ws_size,
                              hipStream_t stream) {
    const float* x  = (const float*)d_in[0];
    const float* b0 = (const float*)d_in[1];
    const float* b1 = (const float*)d_in[2];
    const float* b2 = (const float*)d_in[3];
    const float* a1 = (const float*)d_in[4];
    const float* a2 = (const float*)d_in[5];
    float* y = (float*)d_out;

    k_biquad_scan<<<dim3(B_CH), dim3(512), 0, stream>>>(x, b0, b1, b2, a1, a2, y);
}

// Round 2
// 190.860 us; speedup vs baseline: 2.2306x; 2.2306x over previous
//
#include <hip/hip_runtime.h>

// Biquad DF2T over [B=512, T=48000] fp32, per-channel coeffs.
// One block per channel, 512 threads, 4 stages of 12000 samples.
// Per stage:
//   fill:   prefetched regs -> padded LDS rows (stride 25: 2-way alias, free)
//   (issue next-stage global float4 prefetch; raw barriers keep it in flight)
//   response: 500 threads, zero-state biquad over own 24-sample row
//   scan:   6-round __shfl_up Kogge-Stone (no barriers) + 8 wave aggregates
//           through 192 B LDS (1 barrier), carry-aware affine fold
//   replay: exact reference arithmetic, overwrite LDS row with y
//   writeback: LDS rows -> nontemporal float4 global stores
// Barriers: 4 raw s_barrier/stage (16 total, was ~88), lgkmcnt-only waits so
// the vmcnt prefetch queue is never drained mid-kernel.

#define B_CH   512
#define T_LEN  48000
#define NSTAGE 4
#define STAGE  12000        // samples per stage
#define NACT   500          // active compute threads
#define L      24           // samples per thread per stage
#define STRIDE 25           // padded LDS row stride (floats)
#define NF4    (STAGE / 4)  // 3000 float4 per stage
#define F4ROW  (L / 4)      // 6 float4 per row
#define NPRE   6            // prefetch float4 per thread (ceil(3000/512))
#define NWAVE  8

typedef float f4_t __attribute__((ext_vector_type(4)));

// Raw barrier: producer ds-ops drained (lgkmcnt), vmcnt left in flight.
__device__ __forceinline__ void barrier_lds()
{
    asm volatile("s_waitcnt lgkmcnt(0)" ::: "memory");
    __builtin_amdgcn_s_barrier();
}

__global__ __launch_bounds__(512, 4) void k_biquad_fused(
    const float* __restrict__ x,
    const float* __restrict__ b0v, const float* __restrict__ b1v,
    const float* __restrict__ b2v,
    const float* __restrict__ a1v, const float* __restrict__ a2v,
    float* __restrict__ y)
{
    __shared__ float xl[NACT * STRIDE];   // 12500 floats = 50 KB
    __shared__ float aggP[NWAVE][4];      // wave-aggregate transforms
    __shared__ float aggW[NWAVE][2];      // wave-aggregate responses

    const int b    = blockIdx.x;
    const int t    = threadIdx.x;
    const int lane = t & 63;
    const int wid  = t >> 6;

    const float A1 = a1v[b], A2 = a2v[b];
    const float B0 = b0v[b], B1 = b1v[b], B2 = b2v[b];
    // y-eliminated state form: z1' = c1*x - a1*z1 + z2 ; z2' = c2*x - a2*z1
    const float c1 = B1 - A1 * B0;
    const float c2 = B2 - A2 * B0;

    // G = A^L, A = [[-a1,1],[-a2,0]] (binary exponentiation)
    float G00, G01, G10, G11;
    {
        float m00 = -A1, m01 = 1.f, m10 = -A2, m11 = 0.f;
        float f00 = 1.f, f01 = 0.f, f10 = 0.f, f11 = 1.f;
        int e = L;
        while (e) {
            if (e & 1) {
                const float t00 = f00*m00 + f01*m10, t01 = f00*m01 + f01*m11;
                const float t10 = f10*m00 + f11*m10, t11 = f10*m01 + f11*m11;
                f00 = t00; f01 = t01; f10 = t10; f11 = t11;
            }
            e >>= 1;
            if (!e) break;
            const float s00 = m00*m00 + m01*m10, s01 = m00*m01 + m01*m11;
            const float s10 = m10*m00 + m11*m10, s11 = m10*m01 + m11*m11;
            m00 = s00; m01 = s01; m10 = s10; m11 = s11;
        }
        G00 = f00; G01 = f01; G10 = f10; G11 = f11;
    }

    const float* __restrict__ xb = x + (size_t)b * T_LEN;
    float*       __restrict__ yb = y + (size_t)b * T_LEN;

    // ---- prologue: prefetch stage 0 into registers (24 VGPRs)
    f4_t pre[NPRE];
    #pragma unroll
    for (int k = 0; k < NPRE; ++k) {
        const int g = t + 512 * k;
        if (g < NF4) pre[k] = *(const f4_t*)(xb + 4 * g);
    }

    float cz1 = 0.f, cz2 = 0.f;   // inter-stage carry state

    for (int s = 0; s < NSTAGE; ++s) {
        // ---- fill: prefetched regs -> padded LDS rows
        #pragma unroll
        for (int k = 0; k < NPRE; ++k) {
            const int g = t + 512 * k;
            if (g < NF4) {
                const int own = g / F4ROW;
                const int off = (g - own * F4ROW) * 4;
                float* d = &xl[own * STRIDE + off];
                d[0] = pre[k].x; d[1] = pre[k].y; d[2] = pre[k].z; d[3] = pre[k].w;
            }
        }
        barrier_lds();                                   // B1

        // ---- issue next-stage prefetch; stays in flight across raw barriers
        if (s + 1 < NSTAGE) {
            const float* xn = xb + (s + 1) * STAGE;
            #pragma unroll
            for (int k = 0; k < NPRE; ++k) {
                const int g = t + 512 * k;
                if (g < NF4) pre[k] = *(const f4_t*)(xn + 4 * g);
            }
        }

        // ---- local zero-state response over own 24-sample row
        float P00, P01, P10, P11, w0, w1;
        if (t < NACT) {
            float z1 = 0.f, z2 = 0.f;
            const float* r = &xl[t * STRIDE];
            #pragma unroll
            for (int i = 0; i < L; ++i) {
                const float xn = r[i];
                const float n1 = c1 * xn + z2 - A1 * z1;
                z2 = c2 * xn - A2 * z1;
                z1 = n1;
            }
            P00 = G00; P01 = G01; P10 = G10; P11 = G11; w0 = z1; w1 = z2;
        } else {
            P00 = 1.f; P01 = 0.f; P10 = 0.f; P11 = 1.f; w0 = 0.f; w1 = 0.f;
        }

        // ---- intra-wave inclusive Kogge-Stone via shuffles (no barriers)
        #pragma unroll
        for (int off = 1; off < 64; off <<= 1) {
            const float e00 = __shfl_up(P00, off);
            const float e01 = __shfl_up(P01, off);
            const float e10 = __shfl_up(P10, off);
            const float e11 = __shfl_up(P11, off);
            const float s0  = __shfl_up(w0,  off);
            const float s1  = __shfl_up(w1,  off);
            if (lane >= off) {
                const float n00 = P00*e00 + P01*e10, n01 = P00*e01 + P01*e11;
                const float n10 = P10*e00 + P11*e10, n11 = P10*e01 + P11*e11;
                w0 = P00*s0 + P01*s1 + w0;
                w1 = P10*s0 + P11*s1 + w1;
                P00 = n00; P01 = n01; P10 = n10; P11 = n11;
            }
        }

        // publish wave aggregates (lane 63 inclusive = whole-wave transform)
        if (lane == 63) {
            aggP[wid][0] = P00; aggP[wid][1] = P01;
            aggP[wid][2] = P10; aggP[wid][3] = P11;
            aggW[wid][0] = w0;  aggW[wid][1] = w1;
        }

        // exclusive-within-wave = inclusive shifted down one lane
        float E00 = __shfl_up(P00, 1), E01 = __shfl_up(P01, 1);
        float E10 = __shfl_up(P10, 1), E11 = __shfl_up(P11, 1);
        float Ew0 = __shfl_up(w0, 1),  Ew1 = __shfl_up(w1, 1);
        if (lane == 0) { E00 = 1.f; E01 = 0.f; E10 = 0.f; E11 = 1.f; Ew0 = 0.f; Ew1 = 0.f; }

        barrier_lds();                                   // B2

        // ---- carry-aware fold of wave aggregates (wave-uniform broadcasts)
        // S_k = state entering wave k; snapshot own wid, continue to new carry
        float s0 = cz1, s1 = cz2, my0 = cz1, my1 = cz2;
        #pragma unroll
        for (int k = 0; k < NWAVE; ++k) {
            if (k == wid) { my0 = s0; my1 = s1; }
            const float p0 = aggP[k][0], p1 = aggP[k][1];
            const float p2 = aggP[k][2], p3 = aggP[k][3];
            const float q0 = aggW[k][0], q1 = aggW[k][1];
            const float n0 = p0*s0 + p1*s1 + q0;
            const float n1 = p2*s0 + p3*s1 + q1;
            s0 = n0; s1 = n1;
        }
        cz1 = s0; cz2 = s1;   // carry advanced past this stage

        // this thread's true initial state
        float z1 = E00*my0 + E01*my1 + Ew0;
        float z2 = E10*my0 + E11*my1 + Ew1;

        // ---- replay with exact reference arithmetic, overwrite row with y
        if (t < NACT) {
            float* r = &xl[t * STRIDE];
            #pragma unroll
            for (int i = 0; i < L; ++i) {
                const float xn = r[i];
                const float yn = B0 * xn + z1;
                r[i] = yn;
                const float n1 = B1 * xn - A1 * yn + z2;
                z2 = B2 * xn - A2 * yn;
                z1 = n1;
            }
        }
        barrier_lds();                                   // B3

        // ---- writeback: LDS rows -> nontemporal float4 global stores
        float* ys = yb + s * STAGE;
        #pragma unroll
        for (int k = 0; k < NPRE; ++k) {
            const int g = t + 512 * k;
            if (g < NF4) {
                const int own = g / F4ROW;
                const int off = (g - own * F4ROW) * 4;
                const float* sp = &xl[own * STRIDE + off];
                f4_t v;
                v.x = sp[0]; v.y = sp[1]; v.z = sp[2]; v.w = sp[3];
                __builtin_nontemporal_store(v, (f4_t*)(ys + 4 * g));
            }
        }
        if (s + 1 < NSTAGE) barrier_lds();               // B4: protect xl for next fill
    }
}

extern "C" void kernel_launch(void* const* d_in, const int* in_sizes, int n_in,
                              void* d_out, int out_size, void* d_ws, size_t ws_size,
                              hipStream_t stream) {
    const float* x  = (const float*)d_in[0];
    const float* b0 = (const float*)d_in[1];
    const float* b1 = (const float*)d_in[2];
    const float* b2 = (const float*)d_in[3];
    const float* a1 = (const float*)d_in[4];
    const float* a2 = (const float*)d_in[5];
    float* y = (float*)d_out;

    k_biquad_fused<<<dim3(B_CH), dim3(512), 0, stream>>>(x, b0, b1, b2, a1, a2, y);
}

// Round 3
// 189.296 us; speedup vs baseline: 2.2490x; 1.0083x over previous
//
#include <hip/hip_runtime.h>

// Biquad DF2T over [B=512, T=48000] fp32, per-channel coeffs.
// One block per channel, 512 threads, 4 stages of 12000 samples.
// x is REGISTER-RESIDENT per stage (6 float4/thread, double-buffered);
// LDS is used only to transpose y for coalesced writeback.
// Per stage:
//   (issue next-stage per-thread-row float4 loads; never wait vmcnt mid-loop)
//   response: zero-state biquad over own 24 samples (registers only)
//   scan:     6-round __shfl_up Kogge-Stone + 8 wave aggregates via 192 B LDS
//   barrier A (aggregates visible; also protects xl vs prev writeback)
//   fold -> per-thread initial state; advance inter-stage carry
//   replay:   exact reference arithmetic, y -> LDS rows (stride 25, 2-way free)
//   barrier B
//   writeback: LDS rows -> nontemporal float4 stores; NO barrier after --
//              stores drain while next stage's response/scan run.
// Barriers: 2 per stage (8 total). All LDS waits are lgkmcnt-only.

#define B_CH   512
#define T_LEN  48000
#define NSTAGE 4
#define STAGE  12000        // samples per stage
#define NACT   500          // active compute threads
#define L      24           // samples per thread per stage
#define NF4R   6            // float4 per thread row (L/4)
#define STRIDE 25           // padded LDS row stride (floats)
#define NF4    (STAGE / 4)  // 3000 float4 per stage
#define F4ROW  6
#define NWAVE  8

typedef float f4_t __attribute__((ext_vector_type(4)));

// Raw barrier: producer ds-ops drained (lgkmcnt), vmcnt left in flight.
__device__ __forceinline__ void barrier_lds()
{
    asm volatile("s_waitcnt lgkmcnt(0)" ::: "memory");
    __builtin_amdgcn_s_barrier();
}

__global__ __launch_bounds__(512, 4) void k_biquad_fused(
    const float* __restrict__ x,
    const float* __restrict__ b0v, const float* __restrict__ b1v,
    const float* __restrict__ b2v,
    const float* __restrict__ a1v, const float* __restrict__ a2v,
    float* __restrict__ y)
{
    __shared__ float xl[NACT * STRIDE];   // 12500 floats = 50 KB (y transpose)
    __shared__ float aggP[NWAVE][4];      // wave-aggregate transforms
    __shared__ float aggW[NWAVE][2];      // wave-aggregate responses

    const int b    = blockIdx.x;
    const int t    = threadIdx.x;
    const int lane = t & 63;
    const int wid  = t >> 6;

    const float A1 = a1v[b], A2 = a2v[b];
    const float B0 = b0v[b], B1 = b1v[b], B2 = b2v[b];
    // y-eliminated state form: z1' = c1*x - a1*z1 + z2 ; z2' = c2*x - a2*z1
    const float c1 = B1 - A1 * B0;
    const float c2 = B2 - A2 * B0;

    // G = A^L, A = [[-a1,1],[-a2,0]] (binary exponentiation)
    float G00, G01, G10, G11;
    {
        float m00 = -A1, m01 = 1.f, m10 = -A2, m11 = 0.f;
        float f00 = 1.f, f01 = 0.f, f10 = 0.f, f11 = 1.f;
        int e = L;
        while (e) {
            if (e & 1) {
                const float t00 = f00*m00 + f01*m10, t01 = f00*m01 + f01*m11;
                const float t10 = f10*m00 + f11*m10, t11 = f10*m01 + f11*m11;
                f00 = t00; f01 = t01; f10 = t10; f11 = t11;
            }
            e >>= 1;
            if (!e) break;
            const float s00 = m00*m00 + m01*m10, s01 = m00*m01 + m01*m11;
            const float s10 = m10*m00 + m11*m10, s11 = m10*m01 + m11*m11;
            m00 = s00; m01 = s01; m10 = s10; m11 = s11;
        }
        G00 = f00; G01 = f01; G10 = f10; G11 = f11;
    }

    const float* __restrict__ xb = x + (size_t)b * T_LEN;
    float*       __restrict__ yb = y + (size_t)b * T_LEN;

    float cz1 = 0.f, cz2 = 0.f;   // inter-stage carry state

    // one stage; cur = this stage's x (resident), nxt = prefetch target
    auto do_stage = [&](int s, f4_t (&cur)[NF4R], f4_t (&nxt)[NF4R]) {
        // ---- issue next-stage per-thread-row loads (stay in flight)
        if (s + 1 < NSTAGE && t < NACT) {
            const f4_t* p = (const f4_t*)(xb + (s + 1) * STAGE + t * L);
            #pragma unroll
            for (int k = 0; k < NF4R; ++k) nxt[k] = p[k];
        }

        // ---- local zero-state response (registers only)
        float P00, P01, P10, P11, w0, w1;
        if (t < NACT) {
            float z1 = 0.f, z2 = 0.f;
            #pragma unroll
            for (int k = 0; k < NF4R; ++k) {
                const f4_t v = cur[k];
                { const float xn = v.x; const float n1 = c1*xn + z2 - A1*z1; z2 = c2*xn - A2*z1; z1 = n1; }
                { const float xn = v.y; const float n1 = c1*xn + z2 - A1*z1; z2 = c2*xn - A2*z1; z1 = n1; }
                { const float xn = v.z; const float n1 = c1*xn + z2 - A1*z1; z2 = c2*xn - A2*z1; z1 = n1; }
                { const float xn = v.w; const float n1 = c1*xn + z2 - A1*z1; z2 = c2*xn - A2*z1; z1 = n1; }
            }
            P00 = G00; P01 = G01; P10 = G10; P11 = G11; w0 = z1; w1 = z2;
        } else {
            P00 = 1.f; P01 = 0.f; P10 = 0.f; P11 = 1.f; w0 = 0.f; w1 = 0.f;
        }

        // ---- intra-wave inclusive Kogge-Stone via shuffles (no barriers)
        #pragma unroll
        for (int off = 1; off < 64; off <<= 1) {
            const float e00 = __shfl_up(P00, off);
            const float e01 = __shfl_up(P01, off);
            const float e10 = __shfl_up(P10, off);
            const float e11 = __shfl_up(P11, off);
            const float u0  = __shfl_up(w0,  off);
            const float u1  = __shfl_up(w1,  off);
            if (lane >= off) {
                const float n00 = P00*e00 + P01*e10, n01 = P00*e01 + P01*e11;
                const float n10 = P10*e00 + P11*e10, n11 = P10*e01 + P11*e11;
                w0 = P00*u0 + P01*u1 + w0;
                w1 = P10*u0 + P11*u1 + w1;
                P00 = n00; P01 = n01; P10 = n10; P11 = n11;
            }
        }

        // publish wave aggregates (lane 63 inclusive = whole-wave transform)
        if (lane == 63) {
            aggP[wid][0] = P00; aggP[wid][1] = P01;
            aggP[wid][2] = P10; aggP[wid][3] = P11;
            aggW[wid][0] = w0;  aggW[wid][1] = w1;
        }

        // exclusive-within-wave = inclusive shifted down one lane
        float E00 = __shfl_up(P00, 1), E01 = __shfl_up(P01, 1);
        float E10 = __shfl_up(P10, 1), E11 = __shfl_up(P11, 1);
        float Ew0 = __shfl_up(w0, 1),  Ew1 = __shfl_up(w1, 1);
        if (lane == 0) { E00 = 1.f; E01 = 0.f; E10 = 0.f; E11 = 1.f; Ew0 = 0.f; Ew1 = 0.f; }

        // A: aggregates visible; also guarantees prev writeback's ds_reads
        //    are complete before replay overwrites xl
        barrier_lds();

        // ---- carry-aware fold of wave aggregates (wave-uniform broadcasts)
        float s0 = cz1, s1 = cz2, my0 = cz1, my1 = cz2;
        #pragma unroll
        for (int k = 0; k < NWAVE; ++k) {
            if (k == wid) { my0 = s0; my1 = s1; }
            const float p0 = aggP[k][0], p1 = aggP[k][1];
            const float p2 = aggP[k][2], p3 = aggP[k][3];
            const float q0 = aggW[k][0], q1 = aggW[k][1];
            const float n0 = p0*s0 + p1*s1 + q0;
            const float n1 = p2*s0 + p3*s1 + q1;
            s0 = n0; s1 = n1;
        }
        cz1 = s0; cz2 = s1;   // carry advanced past this stage

        // this thread's true initial state
        float z1 = E00*my0 + E01*my1 + Ew0;
        float z2 = E10*my0 + E11*my1 + Ew1;

        // ---- replay with exact reference arithmetic: registers -> LDS rows
        if (t < NACT) {
            float* r = &xl[t * STRIDE];
            #pragma unroll
            for (int k = 0; k < NF4R; ++k) {
                const f4_t v = cur[k];
                { const float xn = v.x; const float yn = B0*xn + z1; r[4*k+0] = yn;
                  const float n1 = B1*xn - A1*yn + z2; z2 = B2*xn - A2*yn; z1 = n1; }
                { const float xn = v.y; const float yn = B0*xn + z1; r[4*k+1] = yn;
                  const float n1 = B1*xn - A1*yn + z2; z2 = B2*xn - A2*yn; z1 = n1; }
                { const float xn = v.z; const float yn = B0*xn + z1; r[4*k+2] = yn;
                  const float n1 = B1*xn - A1*yn + z2; z2 = B2*xn - A2*yn; z1 = n1; }
                { const float xn = v.w; const float yn = B0*xn + z1; r[4*k+3] = yn;
                  const float n1 = B1*xn - A1*yn + z2; z2 = B2*xn - A2*yn; z1 = n1; }
            }
        }
        barrier_lds();   // B: y rows complete

        // ---- writeback: LDS rows -> nontemporal float4 stores.
        //      No trailing barrier: stores drain under next stage's compute.
        float* ys = yb + s * STAGE;
        #pragma unroll
        for (int k = 0; k < NF4R; ++k) {
            const int g = t + 512 * k;
            if (g < NF4) {
                const int own = g / F4ROW;
                const int off = (g - own * F4ROW) * 4;
                const float* sp = &xl[own * STRIDE + off];
                f4_t v;
                v.x = sp[0]; v.y = sp[1]; v.z = sp[2]; v.w = sp[3];
                __builtin_nontemporal_store(v, (f4_t*)(ys + 4 * g));
            }
        }
    };

    // ---- prologue: load stage 0 rows into registers
    f4_t bufA[NF4R], bufB[NF4R];
    if (t < NACT) {
        const f4_t* p = (const f4_t*)(xb + t * L);
        #pragma unroll
        for (int k = 0; k < NF4R; ++k) bufA[k] = p[k];
    }

    // ping-pong so every buffer index is compile-time constant
    do_stage(0, bufA, bufB);
    do_stage(1, bufB, bufA);
    do_stage(2, bufA, bufB);
    do_stage(3, bufB, bufA);
}

extern "C" void kernel_launch(void* const* d_in, const int* in_sizes, int n_in,
                              void* d_out, int out_size, void* d_ws, size_t ws_size,
                              hipStream_t stream) {
    const float* x  = (const float*)d_in[0];
    const float* b0 = (const float*)d_in[1];
    const float* b1 = (const float*)d_in[2];
    const float* b2 = (const float*)d_in[3];
    const float* a1 = (const float*)d_in[4];
    const float* a2 = (const float*)d_in[5];
    float* y = (float*)d_out;

    k_biquad_fused<<<dim3(B_CH), dim3(512), 0, stream>>>(x, b0, b1, b2, a1, a2, y);
}